// Round 7
// baseline (717.946 us; speedup 1.0000x reference)
//
#include <hip/hip_runtime.h>

// ProjConvReducedI2T — R7: software-pipelined fc (reg double-buffer, no syncs),
// T14 issue-early/write-late staging in conv+mix.

#define EPSc 1e-5f
typedef unsigned short u16;
typedef __bf16 bf16x8 __attribute__((ext_vector_type(8)));
typedef float f32x4 __attribute__((ext_vector_type(4)));

// fixed ws offsets (floats)
static const long OFF_IMG_GLOBAL = 0;        // 32768
static const long OFF_IV         = 32768;    // 32768
static const long OFF_IMG_VEC    = 65536;    // 4096
static const long OFF_CAP_RED    = 69632;    // 1048576  fp32 [128b][128c][64t]
static const long OFF_KERN       = 1118208;  // 1048576  fp32 kern (prologue); reused: part/scsh/pp
static const long OFF_KERN_BF    = 2166784;  // 524288 fl = bf16 [j][i][g][kp][64o][64c']
static const long OFF_CA_BF      = 2691072;  // 16384 fl
static const long OFF_C1W0       = 2707456;  // 8192 fl
static const long OFF_C1W1       = 2715648;  // 16384 fl
static const long OFF_WFC        = 2732032;  // 65536 fl
static const long OFF_CAP_BF     = 2797568;  // 532544 fl : bf16 [128b][65t][128c]
static const long OFF_SHARED1    = 3330112;  // 1048576 fp32 [128b][64t][128o]
static const long OFF_ST_AX0     = 4378688;  // 256
static const long FIXED_END      = 4378944;

__device__ inline u16 f2bf(float f) {
  union { float f; unsigned u; } v; v.f = f;
  unsigned u = v.u;
  return (u16)((u + 0x7FFFu + ((u >> 16) & 1u)) >> 16);
}
__device__ inline float bf2f(u16 u) {
  union { unsigned u; float f; } v; v.u = ((unsigned)u) << 16; return v.f;
}

// ---- img_global + iv ----
__global__ void k_img(const float* __restrict__ img, float* __restrict__ img_global,
                      float* __restrict__ iv) {
  int b = blockIdx.x, tid = threadIdx.x;
  __shared__ float gl[1024];
  __shared__ float red[256];
  float ssq = 0.f;
  for (int l = tid; l < 1024; l += 256) {
    float s = 0.f;
    for (int p = 0; p < 36; ++p) s += img[((long)b*36 + p)*1024 + l];
    float g = s * (1.f/36.f);
    gl[l] = g;
    img_global[(long)b*1024 + l] = g;
    ssq += g*g;
  }
  red[tid] = ssq;
  __syncthreads();
  for (int off = 128; off > 0; off >>= 1) {
    if (tid < off) red[tid] += red[tid+off];
    __syncthreads();
  }
  float inv = rsqrtf(red[0]);
  for (int l = tid; l < 1024; l += 256) iv[(long)b*1024 + l] = gl[l]*inv;
}

// ---- img_vec ----
__global__ void k_imgvec(const float* __restrict__ img_global, const float* __restrict__ W_ri,
                         const float* __restrict__ b_ri, float* __restrict__ img_vec) {
  int b = blockIdx.x, tid = threadIdx.x;
  __shared__ float gl[1024];
  for (int l = tid; l < 1024; l += 128) gl[l] = img_global[(long)b*1024 + l];
  __syncthreads();
  const float* w = W_ri + (long)tid*1024;
  float acc = b_ri[tid];
  for (int l = 0; l < 1024; l += 4) {
    float4 wv = *(const float4*)(w + l);
    float4 gv = *(const float4*)(gl + l);
    acc += wv.x*gv.x + wv.y*gv.y + wv.z*gv.z + wv.w*gv.w;
  }
  img_vec[(long)b*128 + tid] = acc;
}

// ---- cap_red fp32 [b][c][t] ----
__global__ void k_capred(const float* __restrict__ cap, const float* __restrict__ W_rt,
                         const float* __restrict__ b_rt, float* __restrict__ cap_red) {
  int tg = blockIdx.x, b = blockIdx.y, tid = threadIdx.x;
  __shared__ float xs[300*16];
  for (int idx = tid; idx < 16*300; idx += 128) {
    int q = idx / 300, c = idx - q*300;
    xs[c*16 + q] = cap[((long)b*64 + tg*16 + q)*300 + c];
  }
  __syncthreads();
  int o = tid;
  const float* w = W_rt + (long)o*300;
  float acc[16];
  float bb = b_rt[o];
  #pragma unroll
  for (int q = 0; q < 16; ++q) acc[q] = bb;
  for (int c = 0; c < 300; ++c) {
    float wv = w[c];
    const float* xp = &xs[c*16];
    float4 x0 = *(const float4*)(xp);
    float4 x1 = *(const float4*)(xp+4);
    float4 x2 = *(const float4*)(xp+8);
    float4 x3 = *(const float4*)(xp+12);
    acc[0]+=wv*x0.x; acc[1]+=wv*x0.y; acc[2]+=wv*x0.z; acc[3]+=wv*x0.w;
    acc[4]+=wv*x1.x; acc[5]+=wv*x1.y; acc[6]+=wv*x1.z; acc[7]+=wv*x1.w;
    acc[8]+=wv*x2.x; acc[9]+=wv*x2.y; acc[10]+=wv*x2.z; acc[11]+=wv*x2.w;
    acc[12]+=wv*x3.x; acc[13]+=wv*x3.y; acc[14]+=wv*x3.z; acc[15]+=wv*x3.w;
  }
  float* outp = cap_red + ((long)b*128 + o)*64 + tg*16;
  #pragma unroll
  for (int q = 0; q < 16; ++q) outp[q] = acc[q];
}

// ---- cap_red -> cap_bf bf16 [b][t(65)][c], row 64 zero ----
__global__ void k_cap2bf(const float* __restrict__ cap_red, u16* __restrict__ cap_bf) {
  int b = blockIdx.x, tid = threadIdx.x;
  __shared__ float ls[128*64];
  for (int idx = tid; idx < 8192; idx += 256) ls[idx] = cap_red[(long)b*8192 + idx];
  __syncthreads();
  for (int idx = tid; idx < 65*128; idx += 256) {
    int t = idx >> 7, c = idx & 127;
    float v = (t < 64) ? ls[c*64 + t] : 0.f;
    cap_bf[((long)b*65 + t)*128 + c] = f2bf(v);
  }
}

// ---- hypernet kernel gen (fp32) ----
__global__ void k_kerngen(const float* __restrict__ mk_W, const float* __restrict__ mk_b,
                          const float* __restrict__ img_vec, float* __restrict__ kern) {
  int j = blockIdx.x >> 7, kb = blockIdx.x & 127, tid = threadIdx.x;
  int k = kb*128 + tid;
  __shared__ float bl[128*32];
  for (int idx = tid; idx < 4096; idx += 128) {
    int i = idx >> 7, r = idx & 127;
    bl[r*32 + i] = img_vec[idx];
  }
  __syncthreads();
  const float* wrow = mk_W + ((long)j*16384 + k)*128;
  float acc[32];
  #pragma unroll
  for (int i = 0; i < 32; ++i) acc[i] = 0.f;
  for (int r = 0; r < 128; ++r) {
    float w = wrow[r];
    const float* bp = &bl[r*32];
    #pragma unroll
    for (int i = 0; i < 32; ++i) acc[i] += w * bp[i];
  }
  float kb_ = mk_b[(long)j*16384 + k];
  for (int i = 0; i < 32; ++i)
    kern[((long)j*32 + i)*16384 + k] = acc[i] + kb_;
}

// ---- BN on generated kernel rows + deinterleave to bf16 [j][i][g][kp][64o][64c'] ----
__global__ void k_kernbn(const float* __restrict__ kern, const float* __restrict__ wn_g,
                         const float* __restrict__ wn_b, u16* __restrict__ kbf) {
  int j = blockIdx.x >> 5, i = blockIdx.x & 31, o = threadIdx.x;
  const float* row = kern + ((long)((j*32+i)*128 + o))*128;
  float s = 0.f, q = 0.f;
  for (int c = 0; c < 128; ++c) { float v = row[c]; s += v; q += v*v; }
  float mean = s * (1.f/128.f);
  float var = q * (1.f/128.f) - mean*mean;
  float rstd = rsqrtf(var + EPSc);
  float sc = wn_g[j*128+o] * rstd;
  float sh = wn_b[j*128+o] - mean*sc;
  int g = o >> 6, op = o & 63;
  u16* base = kbf + (((long)(j*32+i)*2 + g)*2)*4096 + op*64;
  for (int c = 0; c < 128; ++c) {
    float v = row[c]*sc + sh;
    int kp = c & 1, cp = c >> 1;
    base[(long)kp*4096 + cp] = f2bf(v);
  }
}

// ---- ca_W -> bf16 deinterleaved [j][g][kp][64o][64c'] ----
__global__ void k_ca2bf(const float* __restrict__ caW, u16* __restrict__ cabf) {
  int idx = blockIdx.x*256 + threadIdx.x; // < 32768
  int j = idx >> 14, r = idx & 16383;
  int o = r >> 7, ck = r & 127, cp = ck >> 1, kp = ck & 1;
  int g = o >> 6, op = o & 63;
  cabf[(((long)(j*2+g)*2 + kp))*4096 + op*64 + cp] = f2bf(caW[idx]);
}

// ---- c1_W -> bf16 ----
__global__ void k_c1bf(const float* __restrict__ c1W, u16* __restrict__ w0, u16* __restrict__ w1) {
  int idx = blockIdx.x*256 + threadIdx.x; // < 49152
  if (idx < 16384) { int o = idx >> 7, c = idx & 127; w0[idx] = f2bf(c1W[o*256 + c]); }
  else { int e = idx - 16384; w1[e] = f2bf(c1W[32768 + e]); }
}

// ---- W_fc -> bf16 ----
__global__ void k_wfc2bf(const float* __restrict__ W, u16* __restrict__ out) {
  int idx = (blockIdx.x*256 + threadIdx.x)*4;
  float4 v = *(const float4*)(W + idx);
  u16 o[4] = { f2bf(v.x), f2bf(v.y), f2bf(v.z), f2bf(v.w) };
  *(uint2*)(out + idx) = *(const uint2*)(o);
}

// ---- legacy fp32 grouped conv (shared ax0 branch only) ----
__global__ void k_conv(const float* __restrict__ X, long xstr, int Tin, int Tout,
                       const float* __restrict__ Wt, long wstr,
                       const float* __restrict__ bias, int bstr,
                       float* __restrict__ Y, long ystr) {
  int b = blockIdx.x, ic = blockIdx.y, tid = threadIdx.x;
  __shared__ float xls[128*64];
  const float* Xb = X + (long)ic*xstr + (long)b*128*Tin;
  for (int idx = tid; idx < 128*Tin; idx += 256) {
    int c = idx / Tin, t = idx - c*Tin;
    xls[c*64 + t] = Xb[idx];
  }
  __syncthreads();
  int oi = tid & 63, tq = tid >> 6;
  int o0 = oi*2, g = o0 >> 6, t0 = tq*16;
  const float* wa = Wt + (long)ic*wstr + (long)o0*128;
  const float* wb = wa + 128;
  float acc0[16], acc1[16];
  #pragma unroll
  for (int tt = 0; tt < 16; ++tt) { acc0[tt] = 0.f; acc1[tt] = 0.f; }
  bool f16ok = (t0 + 16 < Tin);
  for (int cp = 0; cp < 64; ++cp) {
    float wa0 = wa[cp*2], wa1 = wa[cp*2+1];
    float wb0 = wb[cp*2], wb1 = wb[cp*2+1];
    const float* row = &xls[(g*64 + cp)*64 + t0];
    float f[17];
    float4 v0 = *(const float4*)(row);
    float4 v1 = *(const float4*)(row+4);
    float4 v2 = *(const float4*)(row+8);
    float4 v3 = *(const float4*)(row+12);
    f[0]=v0.x; f[1]=v0.y; f[2]=v0.z; f[3]=v0.w;
    f[4]=v1.x; f[5]=v1.y; f[6]=v1.z; f[7]=v1.w;
    f[8]=v2.x; f[9]=v2.y; f[10]=v2.z; f[11]=v2.w;
    f[12]=v3.x; f[13]=v3.y; f[14]=v3.z; f[15]=v3.w;
    f[16] = f16ok ? row[16] : 0.f;
    #pragma unroll
    for (int tt = 0; tt < 16; ++tt) {
      acc0[tt] += wa0*f[tt] + wa1*f[tt+1];
      acc1[tt] += wb0*f[tt] + wb1*f[tt+1];
    }
  }
  float bb0 = bias[ic*bstr + o0], bb1 = bias[ic*bstr + o0 + 1];
  float* y0 = Y + (long)ic*ystr + ((long)b*128 + o0)*Tout;
  float* y1 = y0 + Tout;
  #pragma unroll
  for (int tt = 0; tt < 16; ++tt) {
    int t = t0 + tt;
    if (t < Tout) { y0[t] = acc0[tt] + bb0; y1[t] = acc1[tt] + bb1; }
  }
}

// ---- legacy stats (shared branch) ----
__global__ void k_stats(const float* __restrict__ X, long xstr, int Tlen,
                        const float* __restrict__ gp, const float* __restrict__ bp,
                        float* __restrict__ st, int sstr) {
  int c = blockIdx.x, ic = blockIdx.y, tid = threadIdx.x;
  __shared__ float r1[256], r2[256];
  const float* base = X + (long)ic*xstr + (long)c*Tlen;
  int n = 128*Tlen;
  float s = 0.f, q = 0.f;
  for (int idx = tid; idx < n; idx += 256) {
    int b = idx / Tlen, t = idx - b*Tlen;
    float v = base[(long)b*128*Tlen + t];
    s += v; q += v*v;
  }
  r1[tid] = s; r2[tid] = q;
  __syncthreads();
  for (int off = 128; off > 0; off >>= 1) {
    if (tid < off) { r1[tid] += r1[tid+off]; r2[tid] += r2[tid+off]; }
    __syncthreads();
  }
  if (tid == 0) {
    float mean = r1[0] / n;
    float var = r2[0] / n - mean*mean;
    float rstd = rsqrtf(var + EPSc);
    float sc = gp[c]*rstd;
    st[(long)ic*sstr + c] = sc;
    st[(long)ic*sstr + 128 + c] = bp[c] - mean*sc;
  }
}

// ---- shared1 = c1_W[0][:,128:] @ relu(bn(ax0)), out fp32 [b][t][o] ----
__global__ void k_mix_shared(const float* __restrict__ X1, const float* __restrict__ st,
                             const float* __restrict__ W, float* __restrict__ Y) {
  int b = blockIdx.x, tid = threadIdx.x;
  __shared__ float xs[128*64];
  __shared__ float ssc[128], ssh[128];
  int o4 = (tid & 31)*4, t0 = (tid >> 5)*8;
  float acc[4][8];
  #pragma unroll
  for (int r = 0; r < 4; ++r)
    #pragma unroll
    for (int tt = 0; tt < 8; ++tt) acc[r][tt] = 0.f;
  if (tid < 128) { ssc[tid] = st[tid]; ssh[tid] = st[128+tid]; }
  __syncthreads();
  const float* Xb = X1 + (long)b*128*63;
  for (int idx = tid; idx < 128*63; idx += 256) {
    int c = idx / 63, t = idx - c*63;
    xs[c*64 + t] = fmaxf(Xb[idx]*ssc[c] + ssh[c], 0.f);
  }
  __syncthreads();
  for (int c = 0; c < 128; ++c) {
    float4 f0 = *(const float4*)&xs[c*64 + t0];
    float4 f1 = *(const float4*)&xs[c*64 + t0 + 4];
    #pragma unroll
    for (int r = 0; r < 4; ++r) {
      float w = W[(long)(o4+r)*256 + 128 + c];
      acc[r][0] += w*f0.x; acc[r][1] += w*f0.y; acc[r][2] += w*f0.z; acc[r][3] += w*f0.w;
      acc[r][4] += w*f1.x; acc[r][5] += w*f1.y; acc[r][6] += w*f1.z; acc[r][7] += w*f1.w;
    }
  }
  #pragma unroll
  for (int r = 0; r < 4; ++r)
    #pragma unroll
    for (int tt = 0; tt < 8; ++tt) {
      int t = t0 + tt;
      if (t < 63) Y[((long)b*64 + t)*128 + o4 + r] = acc[r][tt];
    }
}

// ---- MFMA grouped conv, pipelined staging (issue-early / write-late) ----
// grid (32, V, NC), caption group of 4. part layout: [i][c][64] = 32 s + 32 q.
__global__ __launch_bounds__(256) void k_conv_mfma3(
    const u16* __restrict__ X, long x_img_str, int tr_stride,
    const u16* __restrict__ kernA, const u16* __restrict__ statA,
    int tvalid, u16* __restrict__ H, int ctot, float* __restrict__ part) {
  int bc = blockIdx.x, v = blockIdx.y, i = blockIdx.z;
  int tid = threadIdx.x, w = tid >> 6, lane = tid & 63;
  int l15 = lane & 15, l4 = lane >> 4;
  int g = v & 1;
  const u16* A = (v >= 2) ? (statA + (long)g*8192)
                          : (kernA + (long)i*16384 + (long)g*8192);
  __shared__ u16 xls[65*64];
  bf16x8 af[2][2];
  #pragma unroll
  for (int kp = 0; kp < 2; ++kp)
    #pragma unroll
    for (int ks = 0; ks < 2; ++ks)
      af[kp][ks] = *(const bf16x8*)(A + ((long)(kp*64 + w*16 + l15))*64 + ks*32 + l4*8);
  int cbase = v*64 + w*16;
  float s[4] = {0.f,0.f,0.f,0.f}, q[4] = {0.f,0.f,0.f,0.f};
  uint4 s0, s1, s2;
  int r0 = tid >> 3, ch0 = tid & 7;
  int r1 = (tid + 256) >> 3, ch1 = tid & 7;  // (tid+256)&7 == tid&7
  auto loadX = [&](int b) {
    const u16* src = X + x_img_str*i + ((long)b*tr_stride)*128 + g*64;
    s0 = *(const uint4*)(src + (long)r0*128 + ch0*8);
    s1 = *(const uint4*)(src + (long)r1*128 + ch1*8);
    if (tid < 8) s2 = *(const uint4*)(src + 64L*128 + tid*8);
  };
  auto writeX = [&]() {
    *(uint4*)(xls + r0*64 + ((ch0 ^ (r0 & 7))*8)) = s0;
    *(uint4*)(xls + r1*64 + ((ch1 ^ (r1 & 7))*8)) = s1;
    if (tid < 8) *(uint4*)(xls + 64*64 + tid*8) = s2;
  };
  loadX(bc*4);
  writeX();
  __syncthreads();
  #pragma unroll
  for (int bb = 0; bb < 4; ++bb) {
    int b = bc*4 + bb;
    if (bb < 3) loadX(b + 1);
    #pragma unroll
    for (int nt = 0; nt < 4; ++nt) {
      f32x4 acc = {0.f,0.f,0.f,0.f};
      #pragma unroll
      for (int kp = 0; kp < 2; ++kp) {
        int row = nt*16 + l15 + kp;
        #pragma unroll
        for (int ks = 0; ks < 2; ++ks) {
          int ch = (ks*4 + l4) ^ (row & 7);
          bf16x8 bf = *(const bf16x8*)(xls + row*64 + ch*8);
          acc = __builtin_amdgcn_mfma_f32_16x16x32_bf16(af[kp][ks], bf, acc, 0, 0, 0);
        }
      }
      int t = nt*16 + l15;
      u16 h4[4] = { f2bf(acc[0]), f2bf(acc[1]), f2bf(acc[2]), f2bf(acc[3]) };
      *(uint2*)(H + ((long)((i*128 + b)*64 + t))*ctot + cbase + l4*4) = *(const uint2*)(h4);
      float m = (t < tvalid) ? 1.f : 0.f;
      #pragma unroll
      for (int r = 0; r < 4; ++r) {
        float vv = acc[r]*m;
        s[r] += vv; q[r] += vv*vv;
      }
    }
    __syncthreads();
    if (bb < 3) { writeX(); __syncthreads(); }
  }
  #pragma unroll
  for (int r = 0; r < 4; ++r) {
    #pragma unroll
    for (int mk = 1; mk < 16; mk <<= 1) {
      s[r] += __shfl_xor(s[r], mk);
      q[r] += __shfl_xor(q[r], mk);
    }
  }
  if (l15 == 0) {
    #pragma unroll
    for (int r = 0; r < 4; ++r) {
      int c = cbase + l4*4 + r;
      long base = ((long)i*ctot + c)*64;
      part[base + bc] = s[r];
      part[base + 32 + bc] = q[r];
    }
  }
}

// ---- reduce 32 partials -> (sc,sh) ----
__global__ void k_finstats2(const float* __restrict__ part, float* __restrict__ scsh,
                            const float* __restrict__ g, const float* __restrict__ bta,
                            int ct, float n, int total) {
  int idx = blockIdx.x*256 + threadIdx.x;
  if (idx >= total) return;
  int c = idx & (ct - 1);
  const float* p = part + (long)idx*64;
  float s = 0.f, q = 0.f;
  #pragma unroll
  for (int k = 0; k < 32; ++k) { s += p[k]; q += p[32+k]; }
  float mean = s / n, var = q / n - mean*mean;
  float sc = g[c] * rsqrtf(var + EPSc);
  scsh[idx*2] = sc;
  scsh[idx*2 + 1] = bta[c] - mean*sc;
}

// ---- MFMA 1x1 mix + fused bn/relu, pipelined staging ----
template<int CK>
__global__ __launch_bounds__(256) void k_mix_mfma3(
    const u16* __restrict__ X, const u16* __restrict__ A,
    const float* __restrict__ scsh,
    const float* __restrict__ c1b, const float* __restrict__ addbuf,
    u16* __restrict__ Q, int tvalid) {
  constexpr int NCH = CK/8;
  constexpr int KST = CK/32;
  constexpr int NST = (64*NCH)/256;
  int bc = blockIdx.x, m = blockIdx.y, i = blockIdx.z;
  int tid = threadIdx.x, w = tid >> 6, lane = tid & 63;
  int l15 = lane & 15, l4 = lane >> 4;
  __shared__ u16 xls[64*CK];
  __shared__ float lsc[CK], lsh[CK];
  for (int c = tid; c < CK; c += 256) {
    lsc[c] = scsh[((long)i*CK + c)*2];
    lsh[c] = scsh[((long)i*CK + c)*2 + 1];
  }
  int oa = m*64 + w*16 + l15;
  bf16x8 af[KST];
  #pragma unroll
  for (int ks = 0; ks < KST; ++ks)
    af[ks] = *(const bf16x8*)(A + (long)oa*CK + ks*32 + l4*8);
  int ob = m*64 + w*16 + l4*4;
  float4 cb;
  cb.x = c1b[ob]; cb.y = c1b[ob+1]; cb.z = c1b[ob+2]; cb.w = c1b[ob+3];
  uint4 st[NST];
  auto loadX = [&](int b) {
    const u16* src = X + ((long)(i*128 + b)*64)*CK;
    #pragma unroll
    for (int k = 0; k < NST; ++k) {
      int idx = tid + k*256;
      st[k] = *(const uint4*)(src + (long)(idx/NCH)*CK + (idx & (NCH-1))*8);
    }
  };
  auto writeX = [&]() {
    #pragma unroll
    for (int k = 0; k < NST; ++k) {
      int idx = tid + k*256;
      int r = idx / NCH, ch = idx & (NCH - 1);
      unsigned dd[4] = {st[k].x, st[k].y, st[k].z, st[k].w};
      int c0 = ch*8;
      u16 o[8];
      #pragma unroll
      for (int pi = 0; pi < 4; ++pi) {
        float v0 = bf2f((u16)(dd[pi] & 0xFFFF));
        float v1 = bf2f((u16)(dd[pi] >> 16));
        v0 = fmaxf(v0*lsc[c0 + pi*2] + lsh[c0 + pi*2], 0.f);
        v1 = fmaxf(v1*lsc[c0 + pi*2 + 1] + lsh[c0 + pi*2 + 1], 0.f);
        o[pi*2] = f2bf(v0); o[pi*2 + 1] = f2bf(v1);
      }
      *(uint4*)(xls + r*CK + (((ch ^ (r & 15)) & (NCH - 1))*8)) = *(const uint4*)o;
    }
  };
  loadX(bc*4);
  __syncthreads();   // lsc/lsh ready
  writeX();
  __syncthreads();
  #pragma unroll
  for (int bb = 0; bb < 4; ++bb) {
    int b = bc*4 + bb;
    if (bb < 3) loadX(b + 1);
    #pragma unroll
    for (int nt = 0; nt < 4; ++nt) {
      f32x4 acc = {0.f,0.f,0.f,0.f};
      int row = nt*16 + l15;
      #pragma unroll
      for (int ks = 0; ks < KST; ++ks) {
        int ch = ((ks*4 + l4) ^ (row & 15)) & (NCH - 1);
        bf16x8 bf = *(const bf16x8*)(xls + row*CK + ch*8);
        acc = __builtin_amdgcn_mfma_f32_16x16x32_bf16(af[ks], bf, acc, 0, 0, 0);
      }
      int t = row;
      if (t < tvalid) {
        float4 ad = {0.f,0.f,0.f,0.f};
        if (addbuf) ad = *(const float4*)(addbuf + ((long)b*64 + t)*128 + ob);
        u16 h4[4] = { f2bf(acc[0] + cb.x + ad.x), f2bf(acc[1] + cb.y + ad.y),
                      f2bf(acc[2] + cb.z + ad.z), f2bf(acc[3] + cb.w + ad.w) };
        *(uint2*)(Q + ((long)((i*128 + b)*64 + t))*128 + ob) = *(const uint2*)(h4);
      }
    }
    __syncthreads();
    if (bb < 3) { writeX(); __syncthreads(); }
  }
}

// ---- fc: W_fc-resident waves, 2-deep Q prefetch, no block reduction ----
// grid (32 capgrp of 4, 4 lslice, NC). pp: [i][b][16][2].
__global__ __launch_bounds__(256) void k_fc4(
    const u16* __restrict__ Qt, const u16* __restrict__ Wb,
    const float* __restrict__ bfc, const float* __restrict__ ivp,
    float* __restrict__ pp) {
  int bg = blockIdx.x, sl = blockIdx.y, i = blockIdx.z;
  int tid = threadIdx.x, w = tid >> 6, lane = tid & 63;
  int l15 = lane & 15, l4 = lane >> 4;
  int lbase = sl*256 + w*64;
  bf16x8 wf[4][4];
  #pragma unroll
  for (int lt = 0; lt < 4; ++lt)
    #pragma unroll
    for (int ks = 0; ks < 4; ++ks)
      wf[lt][ks] = *(const bf16x8*)(Wb + (long)(lbase + lt*16 + l15)*128 + ks*32 + l4*8);
  float bfr[4], ivr[4];
  const float* ivb = ivp + (long)i*1024;
  #pragma unroll
  for (int lt = 0; lt < 4; ++lt) {
    bfr[lt] = bfc[lbase + lt*16 + l15];
    ivr[lt] = ivb[lbase + lt*16 + l15];
  }
  bf16x8 qA[4][4], qB[4][4];
  auto loadQ = [&](bf16x8 (&qf)[4][4], int b) {
    const u16* Qb = Qt + ((long)(i*128 + b))*8192;
    #pragma unroll
    for (int nt = 0; nt < 4; ++nt)
      #pragma unroll
      for (int ks = 0; ks < 4; ++ks)
        qf[nt][ks] = *(const bf16x8*)(Qb + (nt*16 + l15)*128 + ks*32 + l4*8);
  };
  auto computeQ = [&](bf16x8 (&qf)[4][4], int b) {
    float mx[4] = {-3e38f, -3e38f, -3e38f, -3e38f};
    #pragma unroll
    for (int nt = 0; nt < 4; ++nt) {
      #pragma unroll
      for (int lt = 0; lt < 4; ++lt) {
        f32x4 acc = {0.f,0.f,0.f,0.f};
        acc = __builtin_amdgcn_mfma_f32_16x16x32_bf16(qf[nt][0], wf[lt][0], acc, 0,0,0);
        acc = __builtin_amdgcn_mfma_f32_16x16x32_bf16(qf[nt][1], wf[lt][1], acc, 0,0,0);
        acc = __builtin_amdgcn_mfma_f32_16x16x32_bf16(qf[nt][2], wf[lt][2], acc, 0,0,0);
        acc = __builtin_amdgcn_mfma_f32_16x16x32_bf16(qf[nt][3], wf[lt][3], acc, 0,0,0);
        float m01 = fmaxf(acc[0], acc[1]);
        float m23 = fmaxf(acc[2], acc[3]);
        if (nt == 3 && l4 == 3) m23 = -3e38f;   // t=62,63 invalid
        mx[lt] = fmaxf(mx[lt], fmaxf(m01, m23));
      }
    }
    float ssc = 0.f, ddc = 0.f;
    #pragma unroll
    for (int lt = 0; lt < 4; ++lt) {
      float m = mx[lt];
      m = fmaxf(m, __shfl_xor(m, 16));
      m = fmaxf(m, __shfl_xor(m, 32));
      float tv = m + bfr[lt];   // valid on lanes 0-15
      ssc += tv*tv;
      ddc += tv*ivr[lt];
    }
    #pragma unroll
    for (int mk = 1; mk < 16; mk <<= 1) { ssc += __shfl_xor(ssc, mk); ddc += __shfl_xor(ddc, mk); }
    if (lane == 0) {
      long o = (((long)i*128 + b)*16 + sl*4 + w)*2;
      pp[o] = ssc; pp[o+1] = ddc;
    }
  };
  int b0 = bg*4;
  loadQ(qA, b0);
  loadQ(qB, b0 + 1);
  computeQ(qA, b0);
  loadQ(qA, b0 + 2);
  computeQ(qB, b0 + 1);
  loadQ(qB, b0 + 3);
  computeQ(qA, b0 + 2);
  computeQ(qB, b0 + 3);
}

// ---- final: sum 16 partials -> sims ----
__global__ void k_fcred(const float* __restrict__ pp, float* __restrict__ outp) {
  int i = blockIdx.x, b = threadIdx.x;
  const float* p = pp + ((long)i*128 + b)*32;
  float S = 0.f, D = 0.f;
  #pragma unroll
  for (int k = 0; k < 16; ++k) { S += p[k*2]; D += p[k*2+1]; }
  outp[i*128 + b] = D * rsqrtf(S);
}

extern "C" void kernel_launch(void* const* d_in, const int* in_sizes, int n_in,
                              void* d_out, int out_size, void* d_ws, size_t ws_size,
                              hipStream_t stream) {
  (void)in_sizes; (void)n_in; (void)out_size;
  const float* img_embed = (const float*)d_in[0];
  const float* cap_embed = (const float*)d_in[1];
  const float* W_ri  = (const float*)d_in[2];
  const float* b_ri  = (const float*)d_in[3];
  const float* W_rt  = (const float*)d_in[4];
  const float* b_rt  = (const float*)d_in[5];
  const float* mk_W  = (const float*)d_in[6];
  const float* mk_b  = (const float*)d_in[7];
  const float* wn_g  = (const float*)d_in[10];
  const float* wn_b  = (const float*)d_in[11];
  const float* ca_W  = (const float*)d_in[12];
  const float* ca_b  = (const float*)d_in[13];
  const float* bn_g  = (const float*)d_in[14];
  const float* bn_b  = (const float*)d_in[15];
  const float* c1_W  = (const float*)d_in[16];
  const float* c1_b  = (const float*)d_in[17];
  const float* W_fc  = (const float*)d_in[18];
  const float* b_fc  = (const float*)d_in[19];
  float* out = (float*)d_out;
  float* ws  = (float*)d_ws;

  float* img_global = ws + OFF_IMG_GLOBAL;
  float* iv       = ws + OFF_IV;
  float* img_vec  = ws + OFF_IMG_VEC;
  float* cap_red  = ws + OFF_CAP_RED;
  float* kern     = ws + OFF_KERN;
  u16*   kern_bf  = (u16*)(ws + OFF_KERN_BF);
  u16*   ca_bf    = (u16*)(ws + OFF_CA_BF);
  u16*   c1w0     = (u16*)(ws + OFF_C1W0);
  u16*   c1w1     = (u16*)(ws + OFF_C1W1);
  u16*   wfcb     = (u16*)(ws + OFF_WFC);
  u16*   cap_bf   = (u16*)(ws + OFF_CAP_BF);
  float* shared1  = ws + OFF_SHARED1;
  float* st_ax0   = ws + OFF_ST_AX0;

  // choose images-per-pass from ws_size (deterministic -> graph-safe)
  int NC = 4;
  {
    auto need = [](long nc) -> size_t { return (size_t)(FIXED_END + nc*2621440L + 128) * 4u; };
    if (ws_size >= need(32)) NC = 32;
    else if (ws_size >= need(16)) NC = 16;
    else if (ws_size >= need(8)) NC = 8;
  }

  // kern region reused after prologue: stats partials (32 slots) + scsh + fc partials
  float* part  = ws + OFF_KERN;                    // NC*ctot*64 <= 524288 fl
  float* scsh0 = ws + OFF_KERN + 524288;           // NC*256
  float* scsh1 = ws + OFF_KERN + 524288 + 8192;    // NC*512
  float* pp    = ws + OFF_KERN + 524288 + 8192 + 16384; // NC*4096

  // dynamic activation buffers
  long base = FIXED_END;
  float* ax0f = ws + base;                      // prologue fp32 ax0 (in P0 region)
  u16* P0 = (u16*)(ws + base);
  u16* Q0 = (u16*)(ws + base + (long)NC*524288);
  u16* H1 = (u16*)(ws + base + (long)NC*524288*2 + 64);
  u16* Q1 = (u16*)(ws + base + (long)NC*524288*2 + 64 + (long)NC*1048576);

  // prologue
  k_img<<<32, 256, 0, stream>>>(img_embed, img_global, iv);
  k_imgvec<<<32, 128, 0, stream>>>(img_global, W_ri, b_ri, img_vec);
  k_capred<<<dim3(4,128), 128, 0, stream>>>(cap_embed, W_rt, b_rt, cap_red);
  k_cap2bf<<<128, 256, 0, stream>>>(cap_red, cap_bf);
  k_kerngen<<<256, 128, 0, stream>>>(mk_W, mk_b, img_vec, kern);
  k_kernbn<<<64, 128, 0, stream>>>(kern, wn_g, wn_b, kern_bf);
  k_ca2bf<<<128, 256, 0, stream>>>(ca_W, ca_bf);
  k_c1bf<<<192, 256, 0, stream>>>(c1_W, c1w0, c1w1);
  k_wfc2bf<<<128, 256, 0, stream>>>(W_fc, wfcb);

  // shared layer-0 static branch (fp32)
  k_conv<<<dim3(128,1), 256, 0, stream>>>(cap_red, 0, 64, 63, ca_W, 0, ca_b, 0, ax0f, 0);
  k_stats<<<dim3(128,1), 256, 0, stream>>>(ax0f, 0, 63, bn_g+128, bn_b+128, st_ax0, 0);
  k_mix_shared<<<128, 256, 0, stream>>>(ax0f, st_ax0, c1_W, shared1);

  for (int ch = 0; ch < 32/NC; ++ch) {
    int i0 = ch*NC;
    // layer 0 dynamic conv (biases cancel in BN)
    k_conv_mfma3<<<dim3(32,2,NC), 256, 0, stream>>>(
        cap_bf, 0L, 65, kern_bf + (long)i0*16384, ca_bf, 63, P0, 128, part);
    k_finstats2<<<dim3((NC*128+255)/256), 256, 0, stream>>>(
        part, scsh0, bn_g, bn_b, 128, 8064.f, NC*128);
    k_mix_mfma3<128><<<dim3(32,2,NC), 256, 0, stream>>>(
        P0, c1w0, scsh0, c1_b, shared1, Q0, 63);
    // layer 1: generated (v=0,1) + static (v=2,3)
    k_conv_mfma3<<<dim3(32,4,NC), 256, 0, stream>>>(
        Q0, 1048576L, 64, kern_bf + (long)(32 + i0)*16384, ca_bf + 16384, 62, H1, 256, part);
    k_finstats2<<<dim3((NC*256+255)/256), 256, 0, stream>>>(
        part, scsh1, bn_g + 256, bn_b + 256, 256, 7936.f, NC*256);
    k_mix_mfma3<256><<<dim3(32,2,NC), 256, 0, stream>>>(
        H1, c1w1, scsh1, c1_b + 128, nullptr, Q1, 62);
    // fc: weight-resident MFMA with prefetch + partial reduce
    k_fc4<<<dim3(32,4,NC), 256, 0, stream>>>(
        Q1, wfcb, b_fc, iv + (long)i0*1024, pp);
    k_fcred<<<NC, 128, 0, stream>>>(pp, out + i0*128);
  }
}

// Round 8
// 606.152 us; speedup vs baseline: 1.1844x; 1.1844x over previous
//
#include <hip/hip_runtime.h>

// ProjConvReducedI2T — R8: fc = R6-compute + barrier-free epilogue (VGPR fix);
// conv/mix reverted to R6 versions; prologue MFMA-ized (shared branch + fused kerngen/BN).

#define EPSc 1e-5f
typedef unsigned short u16;
typedef __bf16 bf16x8 __attribute__((ext_vector_type(8)));
typedef float f32x4 __attribute__((ext_vector_type(4)));

// fixed ws offsets (floats)
static const long OFF_IMG_GLOBAL = 0;        // 32768
static const long OFF_IV         = 32768;    // 32768
static const long OFF_IMG_VEC    = 65536;    // 4096
static const long OFF_CAP_RED    = 69632;    // 1048576  fp32 [128b][128c][64t]
static const long OFF_KERN       = 1118208;  // 1048576  scratch: part/scsh0/scsh1/pp
static const long OFF_KERN_BF    = 2166784;  // 524288 fl = bf16 [j][i][g][kp][64o][64c']
static const long OFF_CA_BF      = 2691072;  // 16384 fl
static const long OFF_C1W0      = 2707456;   // 8192 fl  (c1_W[0][:, :128])
static const long OFF_C1W0X     = 2715648;   // 8192 fl  (c1_W[0][:, 128:])
static const long OFF_C1W1      = 2723840;   // 16384 fl (c1_W[1] full)
static const long OFF_WFC       = 2740224;   // 65536 fl
static const long OFF_CAP_BF    = 2805760;   // 532544 fl : bf16 [128b][65t][128c]
static const long OFF_SHARED1   = 3338304;   // 1048576 fp32 [128b][64t][128o]
static const long OFF_SCSHS     = 4386880;   // 256 (shared-branch sc/sh)
static const long FIXED_END     = 4387136;

__device__ inline u16 f2bf(float f) {
  union { float f; unsigned u; } v; v.f = f;
  unsigned u = v.u;
  return (u16)((u + 0x7FFFu + ((u >> 16) & 1u)) >> 16);
}
__device__ inline float bf2f(u16 u) {
  union { unsigned u; float f; } v; v.u = ((unsigned)u) << 16; return v.f;
}

// ---- img_global + iv ----
__global__ void k_img(const float* __restrict__ img, float* __restrict__ img_global,
                      float* __restrict__ iv) {
  int b = blockIdx.x, tid = threadIdx.x;
  __shared__ float gl[1024];
  __shared__ float red[256];
  float ssq = 0.f;
  for (int l = tid; l < 1024; l += 256) {
    float s = 0.f;
    for (int p = 0; p < 36; ++p) s += img[((long)b*36 + p)*1024 + l];
    float g = s * (1.f/36.f);
    gl[l] = g;
    img_global[(long)b*1024 + l] = g;
    ssq += g*g;
  }
  red[tid] = ssq;
  __syncthreads();
  for (int off = 128; off > 0; off >>= 1) {
    if (tid < off) red[tid] += red[tid+off];
    __syncthreads();
  }
  float inv = rsqrtf(red[0]);
  for (int l = tid; l < 1024; l += 256) iv[(long)b*1024 + l] = gl[l]*inv;
}

// ---- img_vec ----
__global__ void k_imgvec(const float* __restrict__ img_global, const float* __restrict__ W_ri,
                         const float* __restrict__ b_ri, float* __restrict__ img_vec) {
  int b = blockIdx.x, tid = threadIdx.x;
  __shared__ float gl[1024];
  for (int l = tid; l < 1024; l += 128) gl[l] = img_global[(long)b*1024 + l];
  __syncthreads();
  const float* w = W_ri + (long)tid*1024;
  float acc = b_ri[tid];
  for (int l = 0; l < 1024; l += 4) {
    float4 wv = *(const float4*)(w + l);
    float4 gv = *(const float4*)(gl + l);
    acc += wv.x*gv.x + wv.y*gv.y + wv.z*gv.z + wv.w*gv.w;
  }
  img_vec[(long)b*128 + tid] = acc;
}

// ---- cap_red fp32 [b][c][t] ----
__global__ void k_capred(const float* __restrict__ cap, const float* __restrict__ W_rt,
                         const float* __restrict__ b_rt, float* __restrict__ cap_red) {
  int tg = blockIdx.x, b = blockIdx.y, tid = threadIdx.x;
  __shared__ float xs[300*16];
  for (int idx = tid; idx < 16*300; idx += 128) {
    int q = idx / 300, c = idx - q*300;
    xs[c*16 + q] = cap[((long)b*64 + tg*16 + q)*300 + c];
  }
  __syncthreads();
  int o = tid;
  const float* w = W_rt + (long)o*300;
  float acc[16];
  float bb = b_rt[o];
  #pragma unroll
  for (int q = 0; q < 16; ++q) acc[q] = bb;
  for (int c = 0; c < 300; ++c) {
    float wv = w[c];
    const float* xp = &xs[c*16];
    float4 x0 = *(const float4*)(xp);
    float4 x1 = *(const float4*)(xp+4);
    float4 x2 = *(const float4*)(xp+8);
    float4 x3 = *(const float4*)(xp+12);
    acc[0]+=wv*x0.x; acc[1]+=wv*x0.y; acc[2]+=wv*x0.z; acc[3]+=wv*x0.w;
    acc[4]+=wv*x1.x; acc[5]+=wv*x1.y; acc[6]+=wv*x1.z; acc[7]+=wv*x1.w;
    acc[8]+=wv*x2.x; acc[9]+=wv*x2.y; acc[10]+=wv*x2.z; acc[11]+=wv*x2.w;
    acc[12]+=wv*x3.x; acc[13]+=wv*x3.y; acc[14]+=wv*x3.z; acc[15]+=wv*x3.w;
  }
  float* outp = cap_red + ((long)b*128 + o)*64 + tg*16;
  #pragma unroll
  for (int q = 0; q < 16; ++q) outp[q] = acc[q];
}

// ---- cap_red -> cap_bf bf16 [b][t(65)][c], row 64 zero ----
__global__ void k_cap2bf(const float* __restrict__ cap_red, u16* __restrict__ cap_bf) {
  int b = blockIdx.x, tid = threadIdx.x;
  __shared__ float ls[128*64];
  for (int idx = tid; idx < 8192; idx += 256) ls[idx] = cap_red[(long)b*8192 + idx];
  __syncthreads();
  for (int idx = tid; idx < 65*128; idx += 256) {
    int t = idx >> 7, c = idx & 127;
    float v = (t < 64) ? ls[c*64 + t] : 0.f;
    cap_bf[((long)b*65 + t)*128 + c] = f2bf(v);
  }
}

// ---- fused hypernet kernel gen + BN + bf16 deinterleave ----
// grid (2*128): block = (j, o-row). 128 threads = c.
__global__ void k_kerngen2(const float* __restrict__ mk_W, const float* __restrict__ mk_b,
                           const float* __restrict__ wn_g, const float* __restrict__ wn_b,
                           const float* __restrict__ img_vec, u16* __restrict__ kbf) {
  int j = blockIdx.x >> 7, o = blockIdx.x & 127, c = threadIdx.x;
  __shared__ float bl[128*32];    // [r][i]
  __shared__ float ls[128*33];    // [c][i] padded
  __shared__ float ssc[32], ssh[32];
  for (int idx = c; idx < 4096; idx += 128) {
    int i = idx >> 7, r = idx & 127;
    bl[r*32 + i] = img_vec[idx];
  }
  __syncthreads();
  const float* wrow = mk_W + ((long)(j*16384 + o*128 + c))*128;
  float acc[32];
  #pragma unroll
  for (int i = 0; i < 32; ++i) acc[i] = 0.f;
  for (int r = 0; r < 128; ++r) {
    float w = wrow[r];
    const float* bp = &bl[r*32];
    #pragma unroll
    for (int i = 0; i < 32; ++i) acc[i] += w * bp[i];
  }
  float kb_ = mk_b[j*16384 + o*128 + c];
  #pragma unroll
  for (int i = 0; i < 32; ++i) ls[c*33 + i] = acc[i] + kb_;
  __syncthreads();
  if (c < 32) {
    int i = c;
    float s = 0.f, q = 0.f;
    for (int cc = 0; cc < 128; ++cc) { float v = ls[cc*33 + i]; s += v; q += v*v; }
    float mean = s * (1.f/128.f);
    float var = q * (1.f/128.f) - mean*mean;
    float sc = wn_g[j*128+o] * rsqrtf(var + EPSc);
    ssc[i] = sc;
    ssh[i] = wn_b[j*128+o] - mean*sc;
  }
  __syncthreads();
  int g = o >> 6, op = o & 63, kp = c & 1, cp = c >> 1;
  for (int i = 0; i < 32; ++i) {
    float v = ls[c*33 + i]*ssc[i] + ssh[i];
    kbf[((long)((j*32+i)*2 + g)*2 + kp)*4096 + op*64 + cp] = f2bf(v);
  }
}

// ---- ca_W -> bf16 deinterleaved [j][g][kp][64o][64c'] ----
__global__ void k_ca2bf(const float* __restrict__ caW, u16* __restrict__ cabf) {
  int idx = blockIdx.x*256 + threadIdx.x; // < 32768
  int j = idx >> 14, r = idx & 16383;
  int o = r >> 7, ck = r & 127, cp = ck >> 1, kp = ck & 1;
  int g = o >> 6, op = o & 63;
  cabf[(((long)(j*2+g)*2 + kp))*4096 + op*64 + cp] = f2bf(caW[idx]);
}

// ---- c1_W -> bf16: w0a=[0][:, :128], w0x=[0][:,128:], w1=[1] full ----
__global__ void k_c1bf(const float* __restrict__ c1W, u16* __restrict__ w0a,
                       u16* __restrict__ w0x, u16* __restrict__ w1) {
  int idx = blockIdx.x*256 + threadIdx.x; // < 65536
  u16 v = f2bf(c1W[idx]);
  if (idx < 32768) {
    int o = idx >> 8, c = idx & 255;
    if (c < 128) w0a[o*128 + c] = v; else w0x[o*128 + (c-128)] = v;
  } else {
    w1[idx - 32768] = v;
  }
}

// ---- W_fc -> bf16 ----
__global__ void k_wfc2bf(const float* __restrict__ W, u16* __restrict__ out) {
  int idx = (blockIdx.x*256 + threadIdx.x)*4;
  float4 v = *(const float4*)(W + idx);
  u16 o[4] = { f2bf(v.x), f2bf(v.y), f2bf(v.z), f2bf(v.w) };
  *(uint2*)(out + idx) = *(const uint2*)(o);
}

// ---- MFMA grouped conv, caption-loop (4/block), partial stats ----
// grid (32, V, NI). part layout: [i][c][64] = 32 sums + 32 sumsqs.
__global__ __launch_bounds__(256) void k_conv_mfma2(
    const u16* __restrict__ X, long x_img_str, int tr_stride,
    const u16* __restrict__ kernA, const u16* __restrict__ statA,
    int tvalid, u16* __restrict__ H, int ctot, float* __restrict__ part) {
  int bc = blockIdx.x, v = blockIdx.y, i = blockIdx.z;
  int tid = threadIdx.x, w = tid >> 6, lane = tid & 63;
  int l15 = lane & 15, l4 = lane >> 4;
  int g = v & 1;
  const u16* A = (v >= 2) ? (statA + (long)g*8192)
                          : (kernA + (long)i*16384 + (long)g*8192);
  __shared__ u16 xls[65*64];
  bf16x8 af[2][2];
  #pragma unroll
  for (int kp = 0; kp < 2; ++kp)
    #pragma unroll
    for (int ks = 0; ks < 2; ++ks)
      af[kp][ks] = *(const bf16x8*)(A + ((long)(kp*64 + w*16 + l15))*64 + ks*32 + l4*8);
  int cbase = v*64 + w*16;
  float s[4] = {0.f,0.f,0.f,0.f}, q[4] = {0.f,0.f,0.f,0.f};
  for (int bb = 0; bb < 4; ++bb) {
    int b = bc*4 + bb;
    const u16* src = X + x_img_str*i + ((long)b*tr_stride)*128 + g*64;
    __syncthreads();
    for (int idx = tid; idx < 65*8; idx += 256) {
      int r = idx >> 3, ch = idx & 7;
      uint4 d = *(const uint4*)(src + (long)r*128 + ch*8);
      *(uint4*)(xls + r*64 + ((ch ^ (r & 7))*8)) = d;
    }
    __syncthreads();
    #pragma unroll
    for (int nt = 0; nt < 4; ++nt) {
      f32x4 acc = {0.f,0.f,0.f,0.f};
      #pragma unroll
      for (int kp = 0; kp < 2; ++kp) {
        int row = nt*16 + l15 + kp;
        #pragma unroll
        for (int ks = 0; ks < 2; ++ks) {
          int ch = (ks*4 + l4) ^ (row & 7);
          bf16x8 bf = *(const bf16x8*)(xls + row*64 + ch*8);
          acc = __builtin_amdgcn_mfma_f32_16x16x32_bf16(af[kp][ks], bf, acc, 0, 0, 0);
        }
      }
      int t = nt*16 + l15;
      u16 h4[4] = { f2bf(acc[0]), f2bf(acc[1]), f2bf(acc[2]), f2bf(acc[3]) };
      *(uint2*)(H + ((long)((i*128 + b)*64 + t))*ctot + cbase + l4*4) = *(const uint2*)(h4);
      float m = (t < tvalid) ? 1.f : 0.f;
      #pragma unroll
      for (int r = 0; r < 4; ++r) {
        float vv = acc[r]*m;
        s[r] += vv; q[r] += vv*vv;
      }
    }
  }
  #pragma unroll
  for (int r = 0; r < 4; ++r) {
    #pragma unroll
    for (int mk = 1; mk < 16; mk <<= 1) {
      s[r] += __shfl_xor(s[r], mk);
      q[r] += __shfl_xor(q[r], mk);
    }
  }
  if (l15 == 0) {
    #pragma unroll
    for (int r = 0; r < 4; ++r) {
      int c = cbase + l4*4 + r;
      long base = ((long)i*ctot + c)*64;
      part[base + bc] = s[r];
      part[base + 32 + bc] = q[r];
    }
  }
}

// ---- reduce 32 partials -> (sc,sh) ----
__global__ void k_finstats2(const float* __restrict__ part, float* __restrict__ scsh,
                            const float* __restrict__ g, const float* __restrict__ bta,
                            int ct, float n, int total) {
  int idx = blockIdx.x*256 + threadIdx.x;
  if (idx >= total) return;
  int c = idx & (ct - 1);
  const float* p = part + (long)idx*64;
  float s = 0.f, q = 0.f;
  #pragma unroll
  for (int k = 0; k < 32; ++k) { s += p[k]; q += p[32+k]; }
  float mean = s / n, var = q / n - mean*mean;
  float sc = g[c] * rsqrtf(var + EPSc);
  scsh[idx*2] = sc;
  scsh[idx*2 + 1] = bta[c] - mean*sc;
}

// ---- MFMA 1x1 mix + fused bn/relu, caption-loop (4/block) ----
// F32OUT=true: write fp32 (shared1 path). Else bf16 + c1b + optional addbuf.
template<int CK, bool F32OUT>
__global__ __launch_bounds__(256) void k_mix_mfma2(
    const u16* __restrict__ X, const u16* __restrict__ A,
    const float* __restrict__ scsh,
    const float* __restrict__ c1b, const float* __restrict__ addbuf,
    void* __restrict__ Qout, int tvalid) {
  constexpr int NCH = CK/8;
  constexpr int KST = CK/32;
  int bc = blockIdx.x, m = blockIdx.y, i = blockIdx.z;
  int tid = threadIdx.x, w = tid >> 6, lane = tid & 63;
  int l15 = lane & 15, l4 = lane >> 4;
  __shared__ u16 xls[64*CK];
  __shared__ float lsc[CK], lsh[CK];
  for (int c = tid; c < CK; c += 256) {
    lsc[c] = scsh[((long)i*CK + c)*2];
    lsh[c] = scsh[((long)i*CK + c)*2 + 1];
  }
  int oa = m*64 + w*16 + l15;
  bf16x8 af[KST];
  #pragma unroll
  for (int ks = 0; ks < KST; ++ks)
    af[ks] = *(const bf16x8*)(A + (long)oa*CK + ks*32 + l4*8);
  int ob = m*64 + w*16 + l4*4;
  float4 cb = {0.f,0.f,0.f,0.f};
  if (c1b) { cb.x = c1b[ob]; cb.y = c1b[ob+1]; cb.z = c1b[ob+2]; cb.w = c1b[ob+3]; }
  for (int bb = 0; bb < 4; ++bb) {
    int b = bc*4 + bb;
    const u16* src = X + ((long)(i*128 + b)*64)*CK;
    __syncthreads();
    for (int idx = tid; idx < 64*NCH; idx += 256) {
      int r = idx / NCH, ch = idx & (NCH - 1);
      uint4 d = *(const uint4*)(src + (long)r*CK + ch*8);
      unsigned dd[4] = {d.x, d.y, d.z, d.w};
      int c0 = ch*8;
      u16 o[8];
      #pragma unroll
      for (int pi = 0; pi < 4; ++pi) {
        float v0 = bf2f((u16)(dd[pi] & 0xFFFF));
        float v1 = bf2f((u16)(dd[pi] >> 16));
        v0 = fmaxf(v0*lsc[c0 + pi*2] + lsh[c0 + pi*2], 0.f);
        v1 = fmaxf(v1*lsc[c0 + pi*2 + 1] + lsh[c0 + pi*2 + 1], 0.f);
        o[pi*2] = f2bf(v0); o[pi*2 + 1] = f2bf(v1);
      }
      *(uint4*)(xls + r*CK + (((ch ^ (r & 15)) & (NCH - 1))*8)) = *(const uint4*)o;
    }
    __syncthreads();
    #pragma unroll
    for (int nt = 0; nt < 4; ++nt) {
      f32x4 acc = {0.f,0.f,0.f,0.f};
      int row = nt*16 + l15;
      #pragma unroll
      for (int ks = 0; ks < KST; ++ks) {
        int ch = ((ks*4 + l4) ^ (row & 15)) & (NCH - 1);
        bf16x8 bf = *(const bf16x8*)(xls + row*CK + ch*8);
        acc = __builtin_amdgcn_mfma_f32_16x16x32_bf16(af[ks], bf, acc, 0, 0, 0);
      }
      int t = row;
      if (t < tvalid) {
        if constexpr (F32OUT) {
          float4 o4 = { acc[0]+cb.x, acc[1]+cb.y, acc[2]+cb.z, acc[3]+cb.w };
          *(float4*)((float*)Qout + ((long)((i*128 + b)*64 + t))*128 + ob) = o4;
        } else {
          float4 ad = {0.f,0.f,0.f,0.f};
          if (addbuf) ad = *(const float4*)(addbuf + ((long)b*64 + t)*128 + ob);
          u16 h4[4] = { f2bf(acc[0] + cb.x + ad.x), f2bf(acc[1] + cb.y + ad.y),
                        f2bf(acc[2] + cb.z + ad.z), f2bf(acc[3] + cb.w + ad.w) };
          *(uint2*)((u16*)Qout + ((long)((i*128 + b)*64 + t))*128 + ob) = *(const uint2*)(h4);
        }
      }
    }
  }
}

// ---- fc: W_fc-resident waves, single-buffer Q, NO barriers, per-wave partials ----
// grid (16 capgrp of 8, 4 lslice, NI). pp: [i][b][16][2].
__global__ __launch_bounds__(256) void k_fc5(
    const u16* __restrict__ Qt, const u16* __restrict__ Wb,
    const float* __restrict__ bfc, const float* __restrict__ ivp,
    float* __restrict__ pp) {
  int bg = blockIdx.x, sl = blockIdx.y, i = blockIdx.z;
  int tid = threadIdx.x, w = tid >> 6, lane = tid & 63;
  int l15 = lane & 15, l4 = lane >> 4;
  int lbase = sl*256 + w*64;
  bf16x8 wf[4][4];
  #pragma unroll
  for (int lt = 0; lt < 4; ++lt)
    #pragma unroll
    for (int ks = 0; ks < 4; ++ks)
      wf[lt][ks] = *(const bf16x8*)(Wb + (long)(lbase + lt*16 + l15)*128 + ks*32 + l4*8);
  float bfr[4], ivr[4];
  const float* ivb = ivp + (long)i*1024;
  #pragma unroll
  for (int lt = 0; lt < 4; ++lt) {
    bfr[lt] = bfc[lbase + lt*16 + l15];
    ivr[lt] = ivb[lbase + lt*16 + l15];
  }
  for (int bb = 0; bb < 8; ++bb) {
    int b = bg*8 + bb;
    const u16* Qb = Qt + ((long)(i*128 + b))*8192;
    float mx[4] = {-3e38f, -3e38f, -3e38f, -3e38f};
    #pragma unroll
    for (int nt = 0; nt < 4; ++nt) {
      bf16x8 qf[4];
      #pragma unroll
      for (int ks = 0; ks < 4; ++ks)
        qf[ks] = *(const bf16x8*)(Qb + (nt*16 + l15)*128 + ks*32 + l4*8);
      #pragma unroll
      for (int lt = 0; lt < 4; ++lt) {
        f32x4 acc = {0.f,0.f,0.f,0.f};
        acc = __builtin_amdgcn_mfma_f32_16x16x32_bf16(qf[0], wf[lt][0], acc, 0,0,0);
        acc = __builtin_amdgcn_mfma_f32_16x16x32_bf16(qf[1], wf[lt][1], acc, 0,0,0);
        acc = __builtin_amdgcn_mfma_f32_16x16x32_bf16(qf[2], wf[lt][2], acc, 0,0,0);
        acc = __builtin_amdgcn_mfma_f32_16x16x32_bf16(qf[3], wf[lt][3], acc, 0,0,0);
        // D[row t = nt*16 + l4*4 + r][col l = lbase + lt*16 + l15]
        float m01 = fmaxf(acc[0], acc[1]);
        float m23 = fmaxf(acc[2], acc[3]);
        if (nt == 3 && l4 == 3) m23 = -3e38f;   // t=62,63 invalid
        mx[lt] = fmaxf(mx[lt], fmaxf(m01, m23));
      }
    }
    float ssc = 0.f, ddc = 0.f;
    #pragma unroll
    for (int lt = 0; lt < 4; ++lt) {
      float m = mx[lt];
      m = fmaxf(m, __shfl_xor(m, 16));
      m = fmaxf(m, __shfl_xor(m, 32));
      float tv = m + bfr[lt];   // exact on lanes 0-15
      ssc += tv*tv;
      ddc += tv*ivr[lt];
    }
    #pragma unroll
    for (int mk = 1; mk < 16; mk <<= 1) { ssc += __shfl_xor(ssc, mk); ddc += __shfl_xor(ddc, mk); }
    if (lane == 0) {
      long o = (((long)i*128 + b)*16 + sl*4 + w)*2;
      pp[o] = ssc; pp[o+1] = ddc;
    }
  }
}

// ---- final: sum 16 partials -> sims ----
__global__ void k_fcred(const float* __restrict__ pp, float* __restrict__ outp) {
  int i = blockIdx.x, b = threadIdx.x;
  const float* p = pp + ((long)i*128 + b)*32;
  float S = 0.f, D = 0.f;
  #pragma unroll
  for (int k = 0; k < 16; ++k) { S += p[k*2]; D += p[k*2+1]; }
  outp[i*128 + b] = D * rsqrtf(S);
}

extern "C" void kernel_launch(void* const* d_in, const int* in_sizes, int n_in,
                              void* d_out, int out_size, void* d_ws, size_t ws_size,
                              hipStream_t stream) {
  (void)in_sizes; (void)n_in; (void)out_size;
  const float* img_embed = (const float*)d_in[0];
  const float* cap_embed = (const float*)d_in[1];
  const float* W_ri  = (const float*)d_in[2];
  const float* b_ri  = (const float*)d_in[3];
  const float* W_rt  = (const float*)d_in[4];
  const float* b_rt  = (const float*)d_in[5];
  const float* mk_W  = (const float*)d_in[6];
  const float* mk_b  = (const float*)d_in[7];
  const float* wn_g  = (const float*)d_in[10];
  const float* wn_b  = (const float*)d_in[11];
  const float* ca_W  = (const float*)d_in[12];
  const float* bn_g  = (const float*)d_in[14];
  const float* bn_b  = (const float*)d_in[15];
  const float* c1_W  = (const float*)d_in[16];
  const float* c1_b  = (const float*)d_in[17];
  const float* W_fc  = (const float*)d_in[18];
  const float* b_fc  = (const float*)d_in[19];
  float* out = (float*)d_out;
  float* ws  = (float*)d_ws;

  float* img_global = ws + OFF_IMG_GLOBAL;
  float* iv       = ws + OFF_IV;
  float* img_vec  = ws + OFF_IMG_VEC;
  float* cap_red  = ws + OFF_CAP_RED;
  u16*   kern_bf  = (u16*)(ws + OFF_KERN_BF);
  u16*   ca_bf    = (u16*)(ws + OFF_CA_BF);
  u16*   c1w0a    = (u16*)(ws + OFF_C1W0);
  u16*   c1w0x    = (u16*)(ws + OFF_C1W0X);
  u16*   c1w1     = (u16*)(ws + OFF_C1W1);
  u16*   wfcb     = (u16*)(ws + OFF_WFC);
  u16*   cap_bf   = (u16*)(ws + OFF_CAP_BF);
  float* shared1  = ws + OFF_SHARED1;
  float* scshS    = ws + OFF_SCSHS;

  // choose images-per-pass from ws_size (deterministic -> graph-safe)
  int NC = 4;
  {
    auto need = [](long nc) -> size_t { return (size_t)(FIXED_END + nc*2621440L + 128) * 4u; };
    if (ws_size >= need(32)) NC = 32;
    else if (ws_size >= need(16)) NC = 16;
    else if (ws_size >= need(8)) NC = 8;
  }

  // scratch region (old kern slot): stats partials + scsh + fc partials
  float* part  = ws + OFF_KERN;                       // NC*256*64 <= 524288 fl
  float* scsh0 = ws + OFF_KERN + 524288;              // NC*256
  float* scsh1 = ws + OFF_KERN + 524288 + 8192;       // NC*512
  float* pp    = ws + OFF_KERN + 524288 + 8192 + 16384; // NC*4096

  // dynamic activation buffers
  long base = FIXED_END;
  u16* P0 = (u16*)(ws + base);
  u16* Q0 = (u16*)(ws + base + (long)NC*524288);
  u16* H1 = (u16*)(ws + base + (long)NC*524288*2 + 64);
  u16* Q1 = (u16*)(ws + base + (long)NC*524288*2 + 64 + (long)NC*1048576);
  u16* ax0bf = P0;   // prologue scratch (P0 region, free until main loop)

  // prologue
  k_img<<<32, 256, 0, stream>>>(img_embed, img_global, iv);
  k_imgvec<<<32, 128, 0, stream>>>(img_global, W_ri, b_ri, img_vec);
  k_capred<<<dim3(4,128), 128, 0, stream>>>(cap_embed, W_rt, b_rt, cap_red);
  k_cap2bf<<<128, 256, 0, stream>>>(cap_red, cap_bf);
  k_kerngen2<<<256, 128, 0, stream>>>(mk_W, mk_b, wn_g, wn_b, img_vec, kern_bf);
  k_ca2bf<<<128, 256, 0, stream>>>(ca_W, ca_bf);
  k_c1bf<<<256, 256, 0, stream>>>(c1_W, c1w0a, c1w0x, c1w1);
  k_wfc2bf<<<128, 256, 0, stream>>>(W_fc, wfcb);

  // shared layer-0 static branch via MFMA path (biases cancel in BN):
  // ax0 = conv(cap, ca_W[0]) -> stats -> shared1 = c1_W[0][:,128:] @ relu(bn(ax0))
  k_conv_mfma2<<<dim3(32,2,1), 256, 0, stream>>>(
      cap_bf, 0L, 65, ca_bf, ca_bf, 63, ax0bf, 128, part);
  k_finstats2<<<1, 256, 0, stream>>>(part, scshS, bn_g + 128, bn_b + 128, 128, 8064.f, 128);
  k_mix_mfma2<128, true><<<dim3(32,2,1), 256, 0, stream>>>(
      ax0bf, c1w0x, scshS, nullptr, nullptr, shared1, 63);

  for (int ch = 0; ch < 32/NC; ++ch) {
    int i0 = ch*NC;
    // layer 0 dynamic conv
    k_conv_mfma2<<<dim3(32,2,NC), 256, 0, stream>>>(
        cap_bf, 0L, 65, kern_bf + (long)i0*16384, ca_bf, 63, P0, 128, part);
    k_finstats2<<<dim3((NC*128+255)/256), 256, 0, stream>>>(
        part, scsh0, bn_g, bn_b, 128, 8064.f, NC*128);
    k_mix_mfma2<128, false><<<dim3(32,2,NC), 256, 0, stream>>>(
        P0, c1w0a, scsh0, c1_b, shared1, Q0, 63);
    // layer 1: generated (v=0,1) + static (v=2,3)
    k_conv_mfma2<<<dim3(32,4,NC), 256, 0, stream>>>(
        Q0, 1048576L, 64, kern_bf + (long)(32 + i0)*16384, ca_bf + 16384, 62, H1, 256, part);
    k_finstats2<<<dim3((NC*256+255)/256), 256, 0, stream>>>(
        part, scsh1, bn_g + 256, bn_b + 256, 256, 7936.f, NC*256);
    k_mix_mfma2<256, false><<<dim3(32,2,NC), 256, 0, stream>>>(
        H1, c1w1, scsh1, c1_b + 128, nullptr, Q1, 62);
    // fc: weight-resident, barrier-free
    k_fc5<<<dim3(16,4,NC), 256, 0, stream>>>(
        Q1, wfcb, b_fc, iv + (long)i0*1024, pp);
    k_fcred<<<NC, 128, 0, stream>>>(pp, out + i0*128);
  }
}